// Round 1
// baseline (614.956 us; speedup 1.0000x reference)
//
#include <hip/hip_runtime.h>
#include <hip/hip_bf16.h>
#include <stdint.h>

#define B_ 4
#define S_ 2048
#define D_ 1024
#define F_ 4096
#define E_ 8

typedef __attribute__((ext_vector_type(4))) float f32x4;
typedef __attribute__((ext_vector_type(8))) short bf16x8;

__device__ __forceinline__ unsigned short f2bf(float f) {
    union { float f; unsigned int u; } v; v.f = f;
    unsigned int r = v.u + 0x7fffu + ((v.u >> 16) & 1u);
    return (unsigned short)(r >> 16);
}

__device__ __forceinline__ float gelu_tanh(float x) {
    const float c0 = 0.7978845608028654f;  // sqrt(2/pi)
    const float c1 = 0.044715f;
    float x3 = x * x * x;
    return 0.5f * x * (1.0f + tanhf(c0 * (x + c1 * x3)));
}

// ---- prep: x f32 -> bf16 copy, plus per-(b,d) sum over s (for router mean) ----
__global__ void prep_x_kernel(const float* __restrict__ x,
                              unsigned short* __restrict__ xb,
                              float* __restrict__ xsum) {
    const int b = blockIdx.y;
    const int t = threadIdx.x;      // 256 threads -> d-quad
    const int d0 = t * 4;
    const float* xbase = x + (size_t)b * S_ * D_;
    unsigned short* obase = xb + (size_t)b * S_ * D_;
    float s0 = 0.f, s1 = 0.f, s2 = 0.f, s3 = 0.f;
    for (int s = blockIdx.x; s < S_; s += gridDim.x) {
        f32x4 v = *(const f32x4*)(xbase + (size_t)s * D_ + d0);
        ushort4 o;
        o.x = f2bf(v.x); o.y = f2bf(v.y); o.z = f2bf(v.z); o.w = f2bf(v.w);
        *(ushort4*)(obase + (size_t)s * D_ + d0) = o;
        s0 += v.x; s1 += v.y; s2 += v.z; s3 += v.w;
    }
    atomicAdd(&xsum[b * D_ + d0 + 0], s0);
    atomicAdd(&xsum[b * D_ + d0 + 1], s1);
    atomicAdd(&xsum[b * D_ + d0 + 2], s2);
    atomicAdd(&xsum[b * D_ + d0 + 3], s3);
}

// ---- router: logits = (xsum/S) @ rw + rb; softmax over E; ew = mean over B ----
__global__ void router_kernel(const float* __restrict__ xsum,
                              const float* __restrict__ rw,
                              const float* __restrict__ rb,
                              float* __restrict__ ew) {
    __shared__ float logits[B_][E_];
    __shared__ float probs[B_][E_];
    const int t = threadIdx.x;       // 256 = B(4) x E(8) x part(8)
    const int b = t >> 6;
    const int e = (t >> 3) & 7;
    const int part = t & 7;
    float s = 0.f;
    const int dbeg = part * (D_ / 8);
    for (int d = dbeg; d < dbeg + D_ / 8; ++d)
        s += xsum[b * D_ + d] * rw[d * E_ + e];
    s += __shfl_down(s, 4);
    s += __shfl_down(s, 2);
    s += __shfl_down(s, 1);
    if (part == 0) logits[b][e] = s * (1.0f / S_) + rb[e];
    __syncthreads();
    if (t < B_) {
        float mx = -1e30f;
        for (int j = 0; j < E_; ++j) mx = fmaxf(mx, logits[t][j]);
        float sum = 0.f;
        float ex[E_];
        for (int j = 0; j < E_; ++j) { ex[j] = expf(logits[t][j] - mx); sum += ex[j]; }
        for (int j = 0; j < E_; ++j) probs[t][j] = ex[j] / sum;
    }
    __syncthreads();
    if (t < E_) {
        float m = 0.f;
        for (int j = 0; j < B_; ++j) m += probs[j][t];
        ew[t] = m * (1.0f / B_);
    }
}

// ---- merge: dst[i] = bf16( sum_e ew[e] * w[e][i] ) ----
__global__ void merge_w_kernel(const float* __restrict__ w, const float* __restrict__ ew,
                               unsigned short* __restrict__ dst, int n) {
    float e[E_];
#pragma unroll
    for (int i = 0; i < E_; ++i) e[i] = ew[i];
    const size_t total = (size_t)n >> 2;
    for (size_t q = (size_t)blockIdx.x * blockDim.x + threadIdx.x; q < total;
         q += (size_t)gridDim.x * blockDim.x) {
        f32x4 acc = {0.f, 0.f, 0.f, 0.f};
#pragma unroll
        for (int i = 0; i < E_; ++i) {
            f32x4 v = *(const f32x4*)(w + (size_t)i * n + q * 4);
            acc += v * e[i];
        }
        ushort4 o;
        o.x = f2bf(acc.x); o.y = f2bf(acc.y); o.z = f2bf(acc.z); o.w = f2bf(acc.w);
        *(ushort4*)(dst + q * 4) = o;
    }
}

// ---- merge biases in f32 ----
__global__ void merge_b_kernel(const float* __restrict__ w, const float* __restrict__ ew,
                               float* __restrict__ dst, int n) {
    float e[E_];
#pragma unroll
    for (int i = 0; i < E_; ++i) e[i] = ew[i];
    for (int i = blockIdx.x * blockDim.x + threadIdx.x; i < n; i += gridDim.x * blockDim.x) {
        float a = 0.f;
#pragma unroll
        for (int j = 0; j < E_; ++j) a += e[j] * w[(size_t)j * n + i];
        dst[i] = a;
    }
}

// ---- NT bf16 GEMM, m97 structure: 128x128 tile, BK=32, 4 waves, 16x16x32 MFMA ----
// A: [M,K] bf16 row-major; Bm: [N,K] bf16 row-major (B^T layout); C[r,c] = sum_k A[r,k]*Bm[c,k]
// EPI 0: C = bf16(gelu(acc + bias[c]));  EPI 1: C = f32(acc + bias[c])
template <int EPI>
__global__ __launch_bounds__(256) void gemm_nt(const unsigned short* __restrict__ A,
                                               const unsigned short* __restrict__ Bm,
                                               const float* __restrict__ bias,
                                               void* __restrict__ Cout,
                                               int M, int N, int K) {
    __shared__ unsigned short As[128 * 32];
    __shared__ unsigned short Bs[128 * 32];
    const int tid = threadIdx.x;
    const int wave = tid >> 6;
    const int lane = tid & 63;
    const int wr = wave >> 1, wc = wave & 1;
    const int row0 = blockIdx.y * 128;
    const int col0 = blockIdx.x * 128;

    const unsigned short* Ag = A + (size_t)row0 * K;
    const unsigned short* Bg = Bm + (size_t)col0 * K;

    f32x4 acc[4][4];
#pragma unroll
    for (int m = 0; m < 4; ++m)
#pragma unroll
        for (int n = 0; n < 4; ++n) acc[m][n] = (f32x4){0.f, 0.f, 0.f, 0.f};

    const int srow = wave * 32 + (lane >> 2);   // staging row (issue 0)
    const int skoff = (lane & 3) * 8;           // staging k-offset (bf16 elems)

    for (int kt = 0; kt < K; kt += 32) {
#pragma unroll
        for (int i = 0; i < 2; ++i) {
            const unsigned short* ga = Ag + (size_t)(srow + i * 16) * K + kt + skoff;
            const unsigned short* gb = Bg + (size_t)(srow + i * 16) * K + kt + skoff;
            unsigned short* la = &As[(wave * 32 + i * 16) * 32];
            unsigned short* lb = &Bs[(wave * 32 + i * 16) * 32];
            __builtin_amdgcn_global_load_lds((const __attribute__((address_space(1))) void*)ga,
                                             (__attribute__((address_space(3))) void*)la, 16, 0, 0);
            __builtin_amdgcn_global_load_lds((const __attribute__((address_space(1))) void*)gb,
                                             (__attribute__((address_space(3))) void*)lb, 16, 0, 0);
        }
        __syncthreads();
        bf16x8 af[4], bq[4];
#pragma unroll
        for (int m = 0; m < 4; ++m)
            af[m] = *(const bf16x8*)&As[(wr * 64 + m * 16 + (lane & 15)) * 32 + (lane >> 4) * 8];
#pragma unroll
        for (int n = 0; n < 4; ++n)
            bq[n] = *(const bf16x8*)&Bs[(wc * 64 + n * 16 + (lane & 15)) * 32 + (lane >> 4) * 8];
#pragma unroll
        for (int m = 0; m < 4; ++m)
#pragma unroll
            for (int n = 0; n < 4; ++n)
                acc[m][n] = __builtin_amdgcn_mfma_f32_16x16x32_bf16(af[m], bq[n], acc[m][n], 0, 0, 0);
        __syncthreads();
    }

    const int fr = lane & 15;   // C col within fragment
    const int fq = lane >> 4;   // C row group
#pragma unroll
    for (int m = 0; m < 4; ++m) {
#pragma unroll
        for (int n = 0; n < 4; ++n) {
            const int c = col0 + wc * 64 + n * 16 + fr;
            const float bv = bias[c];
#pragma unroll
            for (int v = 0; v < 4; ++v) {
                const int r = row0 + wr * 64 + m * 16 + fq * 4 + v;
                float val = acc[m][n][v] + bv;
                if (EPI == 0) {
                    ((unsigned short*)Cout)[(size_t)r * N + c] = f2bf(gelu_tanh(val));
                } else {
                    ((float*)Cout)[(size_t)r * N + c] = val;
                }
            }
        }
    }
}

extern "C" void kernel_launch(void* const* d_in, const int* in_sizes, int n_in,
                              void* d_out, int out_size, void* d_ws, size_t ws_size,
                              hipStream_t stream) {
    const float* x  = (const float*)d_in[0];
    const float* rw = (const float*)d_in[1];
    const float* rb = (const float*)d_in[2];
    const float* w1 = (const float*)d_in[3];
    const float* b1 = (const float*)d_in[4];
    const float* w2 = (const float*)d_in[5];
    const float* b2 = (const float*)d_in[6];
    float* out = (float*)d_out;

    char* p = (char*)d_ws;
    auto take = [&](size_t bytes) { char* r = p; p += (bytes + 255) & ~(size_t)255; return r; };
    float* xsum          = (float*)take((size_t)B_ * D_ * sizeof(float));
    float* ew            = (float*)take(E_ * sizeof(float));
    float* mb1           = (float*)take(F_ * sizeof(float));
    float* mb2           = (float*)take(D_ * sizeof(float));
    unsigned short* xb   = (unsigned short*)take((size_t)B_ * S_ * D_ * 2);
    unsigned short* mw1b = (unsigned short*)take((size_t)F_ * D_ * 2);
    unsigned short* mw2b = (unsigned short*)take((size_t)D_ * F_ * 2);
    unsigned short* h    = (unsigned short*)take((size_t)B_ * S_ * F_ * 2);

    hipMemsetAsync(xsum, 0, (size_t)B_ * D_ * sizeof(float), stream);
    prep_x_kernel<<<dim3(32, B_), 256, 0, stream>>>(x, xb, xsum);
    router_kernel<<<1, 256, 0, stream>>>(xsum, rw, rb, ew);
    merge_w_kernel<<<2048, 256, 0, stream>>>(w1, ew, mw1b, F_ * D_);
    merge_w_kernel<<<2048, 256, 0, stream>>>(w2, ew, mw2b, D_ * F_);
    merge_b_kernel<<<16, 256, 0, stream>>>(b1, ew, mb1, F_);
    merge_b_kernel<<<4, 256, 0, stream>>>(b2, ew, mb2, D_);
    gemm_nt<0><<<dim3(F_ / 128, (B_ * S_) / 128), 256, 0, stream>>>(xb, mw1b, mb1, h, B_ * S_, F_, D_);
    gemm_nt<1><<<dim3(D_ / 128, (B_ * S_) / 128), 256, 0, stream>>>(h, mw2b, mb2, out, B_ * S_, D_, F_);
}

// Round 2
// 564.184 us; speedup vs baseline: 1.0900x; 1.0900x over previous
//
#include <hip/hip_runtime.h>
#include <hip/hip_bf16.h>
#include <stdint.h>

#define B_ 4
#define S_ 2048
#define D_ 1024
#define F_ 4096
#define E_ 8

typedef __attribute__((ext_vector_type(4))) float f32x4;
typedef __attribute__((ext_vector_type(8))) short bf16x8;

__device__ __forceinline__ unsigned short f2bf(float f) {
    union { float f; unsigned int u; } v; v.f = f;
    unsigned int r = v.u + 0x7fffu + ((v.u >> 16) & 1u);
    return (unsigned short)(r >> 16);
}

__device__ __forceinline__ float gelu_tanh(float x) {
    const float c0 = 0.7978845608028654f;  // sqrt(2/pi)
    const float c1 = 0.044715f;
    float x3 = x * x * x;
    return 0.5f * x * (1.0f + tanhf(c0 * (x + c1 * x3)));
}

// ---- prep: x f32 -> bf16 copy, plus per-(b,d) sum over s (for router mean) ----
__global__ void prep_x_kernel(const float* __restrict__ x,
                              unsigned short* __restrict__ xb,
                              float* __restrict__ xsum) {
    const int b = blockIdx.y;
    const int t = threadIdx.x;      // 256 threads -> d-quad
    const int d0 = t * 4;
    const float* xbase = x + (size_t)b * S_ * D_;
    unsigned short* obase = xb + (size_t)b * S_ * D_;
    float s0 = 0.f, s1 = 0.f, s2 = 0.f, s3 = 0.f;
    for (int s = blockIdx.x; s < S_; s += gridDim.x) {
        f32x4 v = *(const f32x4*)(xbase + (size_t)s * D_ + d0);
        ushort4 o;
        o.x = f2bf(v.x); o.y = f2bf(v.y); o.z = f2bf(v.z); o.w = f2bf(v.w);
        *(ushort4*)(obase + (size_t)s * D_ + d0) = o;
        s0 += v.x; s1 += v.y; s2 += v.z; s3 += v.w;
    }
    atomicAdd(&xsum[b * D_ + d0 + 0], s0);
    atomicAdd(&xsum[b * D_ + d0 + 1], s1);
    atomicAdd(&xsum[b * D_ + d0 + 2], s2);
    atomicAdd(&xsum[b * D_ + d0 + 3], s3);
}

// ---- router: logits = (xsum/S) @ rw + rb; softmax over E; ew = mean over B ----
__global__ void router_kernel(const float* __restrict__ xsum,
                              const float* __restrict__ rw,
                              const float* __restrict__ rb,
                              float* __restrict__ ew) {
    __shared__ float logits[B_][E_];
    __shared__ float probs[B_][E_];
    const int t = threadIdx.x;       // 256 = B(4) x E(8) x part(8)
    const int b = t >> 6;
    const int e = (t >> 3) & 7;
    const int part = t & 7;
    float s = 0.f;
    const int dbeg = part * (D_ / 8);
    for (int d = dbeg; d < dbeg + D_ / 8; ++d)
        s += xsum[b * D_ + d] * rw[d * E_ + e];
    s += __shfl_down(s, 4);
    s += __shfl_down(s, 2);
    s += __shfl_down(s, 1);
    if (part == 0) logits[b][e] = s * (1.0f / S_) + rb[e];
    __syncthreads();
    if (t < B_) {
        float mx = -1e30f;
        for (int j = 0; j < E_; ++j) mx = fmaxf(mx, logits[t][j]);
        float sum = 0.f;
        float ex[E_];
        for (int j = 0; j < E_; ++j) { ex[j] = expf(logits[t][j] - mx); sum += ex[j]; }
        for (int j = 0; j < E_; ++j) probs[t][j] = ex[j] / sum;
    }
    __syncthreads();
    if (t < E_) {
        float m = 0.f;
        for (int j = 0; j < B_; ++j) m += probs[j][t];
        ew[t] = m * (1.0f / B_);
    }
}

// ---- merge: dst[i] = bf16( sum_e ew[e] * w[e][i] ) ----
__global__ void merge_w_kernel(const float* __restrict__ w, const float* __restrict__ ew,
                               unsigned short* __restrict__ dst, int n) {
    float e[E_];
#pragma unroll
    for (int i = 0; i < E_; ++i) e[i] = ew[i];
    const size_t total = (size_t)n >> 2;
    for (size_t q = (size_t)blockIdx.x * blockDim.x + threadIdx.x; q < total;
         q += (size_t)gridDim.x * blockDim.x) {
        f32x4 acc = {0.f, 0.f, 0.f, 0.f};
#pragma unroll
        for (int i = 0; i < E_; ++i) {
            f32x4 v = *(const f32x4*)(w + (size_t)i * n + q * 4);
            acc += v * e[i];
        }
        ushort4 o;
        o.x = f2bf(acc.x); o.y = f2bf(acc.y); o.z = f2bf(acc.z); o.w = f2bf(acc.w);
        *(ushort4*)(dst + q * 4) = o;
    }
}

// ---- fused bias merges (mb1[F], mb2[D]) ----
__global__ void merge_biases(const float* __restrict__ b1, const float* __restrict__ b2,
                             const float* __restrict__ ew,
                             float* __restrict__ mb1, float* __restrict__ mb2) {
    const int i = blockIdx.x * blockDim.x + threadIdx.x;
    float e[E_];
#pragma unroll
    for (int j = 0; j < E_; ++j) e[j] = ew[j];
    if (i < F_) {
        float a = 0.f;
#pragma unroll
        for (int j = 0; j < E_; ++j) a += e[j] * b1[(size_t)j * F_ + i];
        mb1[i] = a;
    } else if (i - F_ < D_) {
        const int i2 = i - F_;
        float a = 0.f;
#pragma unroll
        for (int j = 0; j < E_; ++j) a += e[j] * b2[(size_t)j * D_ + i2];
        mb2[i2] = a;
    }
}

// ---- init out with broadcast bias (gemm2 accumulates atomically on top) ----
__global__ void init_out_kernel(float* __restrict__ out, const float* __restrict__ mb2) {
    const size_t total_q = (size_t)B_ * S_ * D_ / 4;
    for (size_t q = (size_t)blockIdx.x * blockDim.x + threadIdx.x; q < total_q;
         q += (size_t)gridDim.x * blockDim.x) {
        ((f32x4*)out)[q] = ((const f32x4*)mb2)[q & (D_ / 4 - 1)];
    }
}

// ================= 256x256 8-phase bf16 GEMM (T2+T3+T4+T5) =================
// A:[M,K] bf16 rm; Bm:[N,K] bf16 rm. C = A*Bm^T.
// EPI 0: C(bf16) = gelu(acc + bias[c]);  EPI 3: atomicAdd f32 into Cout0.
#define LGKM0() do { asm volatile("s_waitcnt lgkmcnt(0)" ::: "memory"); \
                     __builtin_amdgcn_sched_barrier(0); } while (0)
#define VMCNT(n) asm volatile("s_waitcnt vmcnt(" #n ")" ::: "memory")
#define BARRIER() __builtin_amdgcn_s_barrier()

template <int EPI>
__global__ __launch_bounds__(512, 2) void gemm256(const unsigned short* __restrict__ A,
                                                  const unsigned short* __restrict__ Bm,
                                                  const float* __restrict__ bias,
                                                  void* __restrict__ Cout0,
                                                  int M, int N, int K, int Klen) {
    __shared__ __align__(128) char lds[131072];
    const int tid = threadIdx.x;
    const int wave = tid >> 6, lane = tid & 63;
    const int wr = wave >> 2, wc = wave & 3;
    const int row0 = blockIdx.y * 256, col0 = blockIdx.x * 256;
    const int kt0 = blockIdx.z * Klen;
    const int NI = Klen / 128;             // 2 K-tiles (of 64) per iteration

    // --- per-thread staging source offsets (inverse st_16x32 swizzle) ---
    const int c0 = tid, c1 = tid + 512;
    const int r0c = ((c0 >> 7) << 4) | ((c0 >> 2) & 15);
    const int k0c = (((c0 >> 6) & 1) << 5) | ((((c0 & 3) << 3) ^ (((c0 >> 5) & 1) << 4)));
    const int r1c = ((c1 >> 7) << 4) | ((c1 >> 2) & 15);
    const int k1c = (((c1 >> 6) & 1) << 5) | ((((c1 & 3) << 3) ^ (((c1 >> 5) & 1) << 4)));
    const size_t soff0 = (size_t)r0c * K + k0c;
    const size_t soff1 = (size_t)r1c * K + k1c;

    const unsigned short* pA0 = A + (size_t)row0 * K + kt0;
    const unsigned short* pA1 = pA0 + (size_t)128 * K;
    const unsigned short* pB0 = Bm + (size_t)col0 * K + kt0;
    const unsigned short* pB1 = pB0 + (size_t)128 * K;

    // --- swizzled read lane offset ---
    int lane_off = ((lane & 15) << 6) + ((lane >> 4) << 4);
    lane_off ^= (lane & 8) << 2;
    const int wrOff = wr * 16384;                                   // A half select
    const int wcOff = 32768 + (wc >> 1) * 16384 + (wc & 1) * 8192;  // B half+quad

    f32x4 acc[8][4];
#pragma unroll
    for (int m = 0; m < 8; ++m)
#pragma unroll
        for (int n = 0; n < 4; ++n) acc[m][n] = (f32x4){0.f, 0.f, 0.f, 0.f};
    bf16x8 aF[4][2], bF[4][2];

#define STAGE(ptr, ktb, ldsoff) do { \
    __builtin_amdgcn_global_load_lds((const __attribute__((address_space(1))) void*)((ptr) + (ktb) + soff0), \
        (__attribute__((address_space(3))) void*)(lds + (ldsoff) + wave * 1024), 16, 0, 0); \
    __builtin_amdgcn_global_load_lds((const __attribute__((address_space(1))) void*)((ptr) + (ktb) + soff1), \
        (__attribute__((address_space(3))) void*)(lds + (ldsoff) + wave * 1024 + 8192), 16, 0, 0); \
  } while (0)

#define RDA4(MB, BUFB) do { _Pragma("unroll") for (int m = 0; m < 4; ++m) { \
    aF[m][0] = *(const bf16x8*)(lds + (BUFB) + wrOff + ((MB) + m) * 2048 + lane_off); \
    aF[m][1] = *(const bf16x8*)(lds + (BUFB) + wrOff + ((MB) + m) * 2048 + 1024 + lane_off); } } while (0)

#define RDB2(NB, BUFB) do { _Pragma("unroll") for (int n = 0; n < 2; ++n) { \
    bF[(NB) + n][0] = *(const bf16x8*)(lds + (BUFB) + wcOff + ((NB) + n) * 2048 + lane_off); \
    bF[(NB) + n][1] = *(const bf16x8*)(lds + (BUFB) + wcOff + ((NB) + n) * 2048 + 1024 + lane_off); } } while (0)

#define MFMAQ(MB, NB) do { \
    __builtin_amdgcn_s_setprio(1); \
    _Pragma("unroll") for (int m = 0; m < 4; ++m) \
    _Pragma("unroll") for (int n = 0; n < 2; ++n) \
    _Pragma("unroll") for (int ks = 0; ks < 2; ++ks) \
      acc[(MB) + m][(NB) + n] = __builtin_amdgcn_mfma_f32_16x16x32_bf16( \
          aF[m][ks], bF[(NB) + n][ks], acc[(MB) + m][(NB) + n], 0, 0, 0); \
    __builtin_amdgcn_s_setprio(0); \
  } while (0)

    // --- prologue: stage tile0 (A+B) and tile1 (B only); 12 loads ---
    STAGE(pA0, 0, 0);
    STAGE(pA1, 0, 16384);
    STAGE(pB0, 0, 32768);
    STAGE(pB1, 0, 49152);
    STAGE(pB0, 64, 65536 + 32768);
    STAGE(pB1, 64, 65536 + 49152);

    for (int i = 0; i < NI; ++i) {
        const int t = 2 * i;
        const int ktN1 = (t + 1) * 64, ktN2 = (t + 2) * 64, ktN3 = (t + 3) * 64;
        const bool last = (i == NI - 1);

        VMCNT(4);
        BARRIER();
        // P1: read A(m0-3)+B(n0-1) buf0; stage A(t+1) h0 -> buf1
        RDA4(0, 0); RDB2(0, 0);
        STAGE(pA0, ktN1, 65536);
        LGKM0();
        MFMAQ(0, 0);
        // P2: read B(n2-3) buf0; stage A(t+1) h1 -> buf1
        RDB2(2, 0);
        STAGE(pA1, ktN1, 65536 + 16384);
        LGKM0();
        MFMAQ(0, 2);
        BARRIER();
        // P3: read A(m4-7) buf0; stage B(t+2) h0 -> buf0
        RDA4(4, 0);
        if (!last) STAGE(pB0, ktN2, 32768);
        LGKM0();
        MFMAQ(4, 2);
        // P4: stage B(t+2) h1 -> buf0; MFMA reuses regs
        if (!last) STAGE(pB1, ktN2, 49152);
        MFMAQ(4, 0);
        if (last) { VMCNT(0); } else { VMCNT(4); }
        BARRIER();
        // P5: read A(m0-3)+B(n0-1) buf1; stage A(t+2) h0 -> buf0
        RDA4(0, 65536); RDB2(0, 65536);
        if (!last) STAGE(pA0, ktN2, 0);
        LGKM0();
        MFMAQ(0, 0);
        // P6: read B(n2-3) buf1; stage A(t+2) h1 -> buf0
        RDB2(2, 65536);
        if (!last) STAGE(pA1, ktN2, 16384);
        LGKM0();
        MFMAQ(0, 2);
        BARRIER();
        // P7: read A(m4-7) buf1; stage B(t+3) h0 -> buf1
        RDA4(4, 65536);
        if (!last) STAGE(pB0, ktN3, 65536 + 32768);
        LGKM0();
        MFMAQ(4, 2);
        // P8: stage B(t+3) h1 -> buf1
        if (!last) STAGE(pB1, ktN3, 65536 + 49152);
        MFMAQ(4, 0);
    }

    // --- epilogue ---
    const int fr = lane & 15, fq = lane >> 4;
    if (EPI == 0) {
        unsigned short* dst = (unsigned short*)Cout0;
#pragma unroll
        for (int n = 0; n < 4; ++n) {
            const int c = col0 + wc * 64 + n * 16 + fr;
            const float bv = bias[c];
#pragma unroll
            for (int m = 0; m < 8; ++m) {
                const int rb = row0 + wr * 128 + m * 16 + fq * 4;
#pragma unroll
                for (int v = 0; v < 4; ++v) {
                    float val = acc[m][n][v] + bv;
                    dst[(size_t)(rb + v) * N + c] = f2bf(gelu_tanh(val));
                }
            }
        }
    } else {
        float* dst = (float*)Cout0;
#pragma unroll
        for (int n = 0; n < 4; ++n) {
            const int c = col0 + wc * 64 + n * 16 + fr;
#pragma unroll
            for (int m = 0; m < 8; ++m) {
                const int rb = row0 + wr * 128 + m * 16 + fq * 4;
#pragma unroll
                for (int v = 0; v < 4; ++v)
                    atomicAdd(&dst[(size_t)(rb + v) * N + c], acc[m][n][v]);
            }
        }
    }
#undef STAGE
#undef RDA4
#undef RDB2
#undef MFMAQ
}

extern "C" void kernel_launch(void* const* d_in, const int* in_sizes, int n_in,
                              void* d_out, int out_size, void* d_ws, size_t ws_size,
                              hipStream_t stream) {
    const float* x  = (const float*)d_in[0];
    const float* rw = (const float*)d_in[1];
    const float* rb = (const float*)d_in[2];
    const float* w1 = (const float*)d_in[3];
    const float* b1 = (const float*)d_in[4];
    const float* w2 = (const float*)d_in[5];
    const float* b2 = (const float*)d_in[6];
    float* out = (float*)d_out;

    char* p = (char*)d_ws;
    auto take = [&](size_t bytes) { char* r = p; p += (bytes + 255) & ~(size_t)255; return r; };
    float* xsum          = (float*)take((size_t)B_ * D_ * sizeof(float));
    float* ew            = (float*)take(E_ * sizeof(float));
    float* mb1           = (float*)take(F_ * sizeof(float));
    float* mb2           = (float*)take(D_ * sizeof(float));
    unsigned short* xb   = (unsigned short*)take((size_t)B_ * S_ * D_ * 2);
    unsigned short* mw1b = (unsigned short*)take((size_t)F_ * D_ * 2);
    unsigned short* mw2b = (unsigned short*)take((size_t)D_ * F_ * 2);
    unsigned short* h    = (unsigned short*)take((size_t)B_ * S_ * F_ * 2);

    hipMemsetAsync(xsum, 0, (size_t)B_ * D_ * sizeof(float), stream);
    prep_x_kernel<<<dim3(128, B_), 256, 0, stream>>>(x, xb, xsum);
    router_kernel<<<1, 256, 0, stream>>>(xsum, rw, rb, ew);
    merge_w_kernel<<<2048, 256, 0, stream>>>(w1, ew, mw1b, F_ * D_);
    merge_w_kernel<<<2048, 256, 0, stream>>>(w2, ew, mw2b, D_ * F_);
    merge_biases<<<(F_ + D_) / 256, 256, 0, stream>>>(b1, b2, ew, mb1, mb2);
    init_out_kernel<<<2048, 256, 0, stream>>>(out, mb2);
    // h = gelu(xb @ mw1b^T + mb1)   [M=8192, N=4096, K=1024]
    gemm256<0><<<dim3(F_ / 256, (B_ * S_) / 256, 1), 512, 0, stream>>>(
        xb, mw1b, mb1, h, B_ * S_, F_, D_, D_);
    // out += h @ mw2b^T   [M=8192, N=1024, K=4096, split-K=2]
    gemm256<3><<<dim3(D_ / 256, (B_ * S_) / 256, 2), 512, 0, stream>>>(
        h, mw2b, nullptr, out, B_ * S_, D_, F_, F_ / 2);
}

// Round 4
// 498.707 us; speedup vs baseline: 1.2331x; 1.1313x over previous
//
#include <hip/hip_runtime.h>
#include <hip/hip_bf16.h>
#include <stdint.h>

#define B_ 4
#define S_ 2048
#define D_ 1024
#define F_ 4096
#define E_ 8

typedef __attribute__((ext_vector_type(4))) float f32x4;
typedef __attribute__((ext_vector_type(8))) short bf16x8;

__device__ __forceinline__ unsigned short f2bf(float f) {
    union { float f; unsigned int u; } v; v.f = f;
    unsigned int r = v.u + 0x7fffu + ((v.u >> 16) & 1u);
    return (unsigned short)(r >> 16);
}

__device__ __forceinline__ float gelu_tanh(float x) {
    const float c0 = 0.7978845608028654f;  // sqrt(2/pi)
    const float c1 = 0.044715f;
    float u = c0 * (x + c1 * x * x * x);
    float t = 1.0f - 2.0f / (__expf(2.0f * u) + 1.0f);   // tanh(u), exact at +-inf
    return 0.5f * x * (1.0f + t);
}

// ---- prep: x f32 -> bf16 copy, plus per-(b,d) sum over s (for router mean) ----
__global__ void prep_x_kernel(const float* __restrict__ x,
                              unsigned short* __restrict__ xb,
                              float* __restrict__ xsum) {
    const int b = blockIdx.y;
    const int t = threadIdx.x;      // 256 threads -> d-quad
    const int d0 = t * 4;
    const float* xbase = x + (size_t)b * S_ * D_;
    unsigned short* obase = xb + (size_t)b * S_ * D_;
    float s0 = 0.f, s1 = 0.f, s2 = 0.f, s3 = 0.f;
    for (int s = blockIdx.x; s < S_; s += gridDim.x) {
        f32x4 v = *(const f32x4*)(xbase + (size_t)s * D_ + d0);
        ushort4 o;
        o.x = f2bf(v.x); o.y = f2bf(v.y); o.z = f2bf(v.z); o.w = f2bf(v.w);
        *(ushort4*)(obase + (size_t)s * D_ + d0) = o;
        s0 += v.x; s1 += v.y; s2 += v.z; s3 += v.w;
    }
    atomicAdd(&xsum[b * D_ + d0 + 0], s0);
    atomicAdd(&xsum[b * D_ + d0 + 1], s1);
    atomicAdd(&xsum[b * D_ + d0 + 2], s2);
    atomicAdd(&xsum[b * D_ + d0 + 3], s3);
}

// ---- router: logits = (xsum/S) @ rw + rb; softmax over E; ew = mean over B ----
__global__ void router_kernel(const float* __restrict__ xsum,
                              const float* __restrict__ rw,
                              const float* __restrict__ rb,
                              float* __restrict__ ew) {
    __shared__ float logits[B_][E_];
    __shared__ float probs[B_][E_];
    const int t = threadIdx.x;       // 256 = B(4) x E(8) x part(8)
    const int b = t >> 6;
    const int e = (t >> 3) & 7;
    const int part = t & 7;
    float s = 0.f;
    const int dbeg = part * (D_ / 8);
    for (int d = dbeg; d < dbeg + D_ / 8; ++d)
        s += xsum[b * D_ + d] * rw[d * E_ + e];
    s += __shfl_down(s, 4);
    s += __shfl_down(s, 2);
    s += __shfl_down(s, 1);
    if (part == 0) logits[b][e] = s * (1.0f / S_) + rb[e];
    __syncthreads();
    if (t < B_) {
        float mx = -1e30f;
        for (int j = 0; j < E_; ++j) mx = fmaxf(mx, logits[t][j]);
        float sum = 0.f;
        float ex[E_];
        for (int j = 0; j < E_; ++j) { ex[j] = expf(logits[t][j] - mx); sum += ex[j]; }
        for (int j = 0; j < E_; ++j) probs[t][j] = ex[j] / sum;
    }
    __syncthreads();
    if (t < E_) {
        float m = 0.f;
        for (int j = 0; j < B_; ++j) m += probs[j][t];
        ew[t] = m * (1.0f / B_);
    }
}

// ---- fused merge: mw1b, mw2b (bf16), mb1, mb2 (f32) in one launch ----
__global__ void merge_all_kernel(const float* __restrict__ w1, const float* __restrict__ w2,
                                 const float* __restrict__ b1, const float* __restrict__ b2,
                                 const float* __restrict__ ew,
                                 unsigned short* __restrict__ mw1b, unsigned short* __restrict__ mw2b,
                                 float* __restrict__ mb1, float* __restrict__ mb2) {
    float e[E_];
#pragma unroll
    for (int i = 0; i < E_; ++i) e[i] = ew[i];
    const size_t n = (size_t)F_ * D_;        // elements per expert (both matrices)
    const size_t nq = n >> 2;
    const int half = gridDim.x >> 1;
    const bool first = (int)blockIdx.x < half;
    const float* w = first ? w1 : w2;
    unsigned short* dst = first ? mw1b : mw2b;
    const int bid = first ? blockIdx.x : blockIdx.x - half;
    for (size_t q = (size_t)bid * blockDim.x + threadIdx.x; q < nq;
         q += (size_t)half * blockDim.x) {
        f32x4 acc = {0.f, 0.f, 0.f, 0.f};
#pragma unroll
        for (int i = 0; i < E_; ++i) {
            f32x4 v = *(const f32x4*)(w + (size_t)i * n + q * 4);
            acc += v * e[i];
        }
        ushort4 o;
        o.x = f2bf(acc.x); o.y = f2bf(acc.y); o.z = f2bf(acc.z); o.w = f2bf(acc.w);
        *(ushort4*)(dst + q * 4) = o;
    }
    if (blockIdx.x == gridDim.x - 1) {
        for (int i = threadIdx.x; i < F_ + D_; i += blockDim.x) {
            if (i < F_) {
                float a = 0.f;
#pragma unroll
                for (int j = 0; j < E_; ++j) a += e[j] * b1[(size_t)j * F_ + i];
                mb1[i] = a;
            } else {
                const int i2 = i - F_;
                float a = 0.f;
#pragma unroll
                for (int j = 0; j < E_; ++j) a += e[j] * b2[(size_t)j * D_ + i2];
                mb2[i2] = a;
            }
        }
    }
}

// ======================= shared GEMM helpers =======================
#define LGKM0() do { asm volatile("s_waitcnt lgkmcnt(0)" ::: "memory"); \
                     __builtin_amdgcn_sched_barrier(0); } while (0)
#define VMCNT(n) asm volatile("s_waitcnt vmcnt(" #n ")" ::: "memory")
#define BARRIER() __builtin_amdgcn_s_barrier()

// ============ gemm256: 256x256x(BK=64) 8-phase, gelu->bf16 epilogue ============
// A:[M,K] bf16 rm; Bm:[N,K] bf16 rm. C(bf16) = gelu(A*Bm^T + bias).
__global__ __launch_bounds__(512, 2) void gemm256(const unsigned short* __restrict__ A,
                                                  const unsigned short* __restrict__ Bm,
                                                  const float* __restrict__ bias,
                                                  unsigned short* __restrict__ Cout,
                                                  int M, int N, int K) {
    __shared__ __align__(128) char lds[131072];
    const int tid = threadIdx.x;
    const int wave = tid >> 6, lane = tid & 63;
    const int wr = wave >> 2, wc = wave & 3;
    // XCD-aware bijective swizzle (nwg multiple of 8)
    const int nbx = N / 256;
    const int wg = blockIdx.y * nbx + blockIdx.x;
    const int nwg = (M / 256) * nbx;
    const int swz = (wg & 7) * (nwg >> 3) + (wg >> 3);
    const int row0 = (swz / nbx) * 256, col0 = (swz % nbx) * 256;
    const int NI = K / 128;            // 2 K-tiles (of 64) per iteration

    // per-thread staging source offsets (inverse st_16x32 swizzle)
    const int c0 = tid, c1 = tid + 512;
    const int r0c = ((c0 >> 7) << 4) | ((c0 >> 2) & 15);
    const int k0c = (((c0 >> 6) & 1) << 5) | ((((c0 & 3) << 3) ^ (((c0 >> 5) & 1) << 4)));
    const int r1c = ((c1 >> 7) << 4) | ((c1 >> 2) & 15);
    const int k1c = (((c1 >> 6) & 1) << 5) | ((((c1 & 3) << 3) ^ (((c1 >> 5) & 1) << 4)));
    const size_t soff0 = (size_t)r0c * K + k0c;
    const size_t soff1 = (size_t)r1c * K + k1c;

    const unsigned short* pA0 = A + (size_t)row0 * K;
    const unsigned short* pA1 = pA0 + (size_t)128 * K;
    const unsigned short* pB0 = Bm + (size_t)col0 * K;
    const unsigned short* pB1 = pB0 + (size_t)128 * K;

    int lane_off = ((lane & 15) << 6) + ((lane >> 4) << 4);
    lane_off ^= (lane & 8) << 2;
    const int wrOff = wr * 16384;
    const int wcOff = 32768 + (wc >> 1) * 16384 + (wc & 1) * 8192;

    f32x4 acc[8][4];
#pragma unroll
    for (int m = 0; m < 8; ++m)
#pragma unroll
        for (int n = 0; n < 4; ++n) acc[m][n] = (f32x4){0.f, 0.f, 0.f, 0.f};
    bf16x8 aF[4][2], bF[4][2];

#define STAGE6(ptr, ktb, ldsoff) do { \
    __builtin_amdgcn_global_load_lds((const __attribute__((address_space(1))) void*)((ptr) + (ktb) + soff0), \
        (__attribute__((address_space(3))) void*)(lds + (ldsoff) + wave * 1024), 16, 0, 0); \
    __builtin_amdgcn_global_load_lds((const __attribute__((address_space(1))) void*)((ptr) + (ktb) + soff1), \
        (__attribute__((address_space(3))) void*)(lds + (ldsoff) + wave * 1024 + 8192), 16, 0, 0); \
  } while (0)

#define RDA46(MB, BUFB) do { _Pragma("unroll") for (int m = 0; m < 4; ++m) { \
    aF[m][0] = *(const bf16x8*)(lds + (BUFB) + wrOff + ((MB) + m) * 2048 + lane_off); \
    aF[m][1] = *(const bf16x8*)(lds + (BUFB) + wrOff + ((MB) + m) * 2048 + 1024 + lane_off); } } while (0)

#define RDB26(NB, BUFB) do { _Pragma("unroll") for (int n = 0; n < 2; ++n) { \
    bF[(NB) + n][0] = *(const bf16x8*)(lds + (BUFB) + wcOff + ((NB) + n) * 2048 + lane_off); \
    bF[(NB) + n][1] = *(const bf16x8*)(lds + (BUFB) + wcOff + ((NB) + n) * 2048 + 1024 + lane_off); } } while (0)

#define MFMAQ6(MB, NB) do { \
    __builtin_amdgcn_s_setprio(1); \
    _Pragma("unroll") for (int m = 0; m < 4; ++m) \
    _Pragma("unroll") for (int n = 0; n < 2; ++n) \
    _Pragma("unroll") for (int ks = 0; ks < 2; ++ks) \
      acc[(MB) + m][(NB) + n] = __builtin_amdgcn_mfma_f32_16x16x32_bf16( \
          aF[m][ks], bF[(NB) + n][ks], acc[(MB) + m][(NB) + n], 0, 0, 0); \
    __builtin_amdgcn_s_setprio(0); \
  } while (0)

    // prologue: tile0 (A+B) and tile1 (B only)
    STAGE6(pA0, 0, 0);
    STAGE6(pA1, 0, 16384);
    STAGE6(pB0, 0, 32768);
    STAGE6(pB1, 0, 49152);
    STAGE6(pB0, 64, 65536 + 32768);
    STAGE6(pB1, 64, 65536 + 49152);

    for (int i = 0; i < NI; ++i) {
        const int t = 2 * i;
        const int ktN1 = (t + 1) * 64, ktN2 = (t + 2) * 64, ktN3 = (t + 3) * 64;
        const bool last = (i == NI - 1);

        VMCNT(4);
        BARRIER();
        RDA46(0, 0); RDB26(0, 0);
        STAGE6(pA0, ktN1, 65536);
        LGKM0();
        MFMAQ6(0, 0);
        RDB26(2, 0);
        STAGE6(pA1, ktN1, 65536 + 16384);
        LGKM0();
        MFMAQ6(0, 2);
        BARRIER();
        RDA46(4, 0);
        if (!last) STAGE6(pB0, ktN2, 32768);
        LGKM0();
        MFMAQ6(4, 2);
        if (!last) STAGE6(pB1, ktN2, 49152);
        MFMAQ6(4, 0);
        if (last) { VMCNT(0); } else { VMCNT(4); }
        BARRIER();
        RDA46(0, 65536); RDB26(0, 65536);
        if (!last) STAGE6(pA0, ktN2, 0);
        LGKM0();
        MFMAQ6(0, 0);
        RDB26(2, 65536);
        if (!last) STAGE6(pA1, ktN2, 16384);
        LGKM0();
        MFMAQ6(0, 2);
        BARRIER();
        RDA46(4, 65536);
        if (!last) STAGE6(pB0, ktN3, 65536 + 32768);
        LGKM0();
        MFMAQ6(4, 2);
        if (!last) STAGE6(pB1, ktN3, 65536 + 49152);
        MFMAQ6(4, 0);
    }

    const int fr = lane & 15, fq = lane >> 4;
#pragma unroll
    for (int n = 0; n < 4; ++n) {
        const int c = col0 + wc * 64 + n * 16 + fr;
        const float bv = bias[c];
#pragma unroll
        for (int m = 0; m < 8; ++m) {
            const int rb = row0 + wr * 128 + m * 16 + fq * 4;
#pragma unroll
            for (int v = 0; v < 4; ++v) {
                float val = acc[m][n][v] + bv;
                Cout[(size_t)(rb + v) * N + c] = f2bf(gelu_tanh(val));
            }
        }
    }
#undef STAGE6
#undef RDA46
#undef RDB26
#undef MFMAQ6
}

// ============ gemm128: 128x256x(BK=64) 8-phase, f32 bias epilogue ============
// A:[M,K] bf16 rm; Bm:[N,K] bf16 rm. C(f32) = A*Bm^T + bias.
// Waves: wr=wave>>2 (M half, 64 rows), wc=wave&3 (N quarter). acc[4][4].
// LDS: A0@0(16K) B0@16K(32K) A1@48K... offsets: A0=0,B0=16384,A1=49152,B1=65536.
__global__ __launch_bounds__(512, 2) void gemm128(const unsigned short* __restrict__ A,
                                                  const unsigned short* __restrict__ Bm,
                                                  const float* __restrict__ bias,
                                                  float* __restrict__ Cout,
                                                  int M, int N, int K) {
    __shared__ __align__(128) char lds[98304];
    const int tid = threadIdx.x;
    const int wave = tid >> 6, lane = tid & 63;
    const int wr = wave >> 2, wc = wave & 3;
    const int nbx = N / 256;
    const int wg = blockIdx.y * nbx + blockIdx.x;
    const int nwg = (M / 128) * nbx;
    const int swz = (wg & 7) * (nwg >> 3) + (wg >> 3);
    const int row0 = (swz / nbx) * 128, col0 = (swz % nbx) * 256;
    const int NI = K / 128;

    const int c0 = tid, c1 = tid + 512;
    const int r0c = ((c0 >> 7) << 4) | ((c0 >> 2) & 15);
    const int k0c = (((c0 >> 6) & 1) << 5) | ((((c0 & 3) << 3) ^ (((c0 >> 5) & 1) << 4)));
    const int r1c = ((c1 >> 7) << 4) | ((c1 >> 2) & 15);
    const int k1c = (((c1 >> 6) & 1) << 5) | ((((c1 & 3) << 3) ^ (((c1 >> 5) & 1) << 4)));
    const size_t soff0 = (size_t)r0c * K + k0c;
    const size_t soff1 = (size_t)r1c * K + k1c;

    const unsigned short* pA  = A + (size_t)row0 * K;
    const unsigned short* pB0 = Bm + (size_t)col0 * K;
    const unsigned short* pB1 = pB0 + (size_t)128 * K;

    int lane_off = ((lane & 15) << 6) + ((lane >> 4) << 4);
    lane_off ^= (lane & 8) << 2;
    const int wcOff = (wc >> 1) * 16384 + (wc & 1) * 8192;  // within B region

    f32x4 acc[4][4];
#pragma unroll
    for (int m = 0; m < 4; ++m)
#pragma unroll
        for (int n = 0; n < 4; ++n) acc[m][n] = (f32x4){0.f, 0.f, 0.f, 0.f};
    bf16x8 aF[2][2], bF[4][2];

#define A0OFF 0
#define B0OFF 16384
#define A1OFF 49152
#define B1OFF 65536

#define STAGE1(ptr, ktb, ldsoff) do { \
    __builtin_amdgcn_global_load_lds((const __attribute__((address_space(1))) void*)((ptr) + (ktb) + soff0), \
        (__attribute__((address_space(3))) void*)(lds + (ldsoff) + wave * 1024), 16, 0, 0); \
    __builtin_amdgcn_global_load_lds((const __attribute__((address_space(1))) void*)((ptr) + (ktb) + soff1), \
        (__attribute__((address_space(3))) void*)(lds + (ldsoff) + wave * 1024 + 8192), 16, 0, 0); \
  } while (0)

#define RDA2(MB, ABASE) do { _Pragma("unroll") for (int j = 0; j < 2; ++j) { \
    aF[j][0] = *(const bf16x8*)(lds + (ABASE) + (wr * 4 + (MB) + j) * 2048 + lane_off); \
    aF[j][1] = *(const bf16x8*)(lds + (ABASE) + (wr * 4 + (MB) + j) * 2048 + 1024 + lane_off); } } while (0)

#define RDB2X(NB, BBASE) do { _Pragma("unroll") for (int n = 0; n < 2; ++n) { \
    bF[(NB) + n][0] = *(const bf16x8*)(lds + (BBASE) + wcOff + ((NB) + n) * 2048 + lane_off); \
    bF[(NB) + n][1] = *(const bf16x8*)(lds + (BBASE) + wcOff + ((NB) + n) * 2048 + 1024 + lane_off); } } while (0)

#define MFMAQ2(MB, NB) do { \
    __builtin_amdgcn_s_setprio(1); \
    _Pragma("unroll") for (int j = 0; j < 2; ++j) \
    _Pragma("unroll") for (int n = 0; n < 2; ++n) \
    _Pragma("unroll") for (int ks = 0; ks < 2; ++ks) \
      acc[(MB) + j][(NB) + n] = __builtin_amdgcn_mfma_f32_16x16x32_bf16( \
          aF[j][ks], bF[(NB) + n][ks], acc[(MB) + j][(NB) + n], 0, 0, 0); \
    __builtin_amdgcn_s_setprio(0); \
  } while (0)

    // prologue: A(0)->A0, B(0)->B0, B(1)->B1   (10 loads)
    STAGE1(pA, 0, A0OFF);
    STAGE1(pB0, 0, B0OFF);
    STAGE1(pB1, 0, B0OFF + 16384);
    STAGE1(pB0, 64, B1OFF);
    STAGE1(pB1, 64, B1OFF + 16384);

    for (int i = 0; i < NI; ++i) {
        const int t = 2 * i;
        const bool last = (i == NI - 1);
        const int kA1 = (t + 1) * 64, kN2 = (t + 2) * 64, kN3 = (t + 3) * 64;

        VMCNT(4);
        BARRIER();
        // P1: read A(m0-1)+B(n0-1) buf0; stage A(t+1)->A1 (always valid)
        RDA2(0, A0OFF); RDB2X(0, B0OFF);
        STAGE1(pA, kA1, A1OFF);
        LGKM0();
        MFMAQ2(0, 0);
        // P2
        RDB2X(2, B0OFF);
        LGKM0();
        MFMAQ2(0, 2);
        BARRIER();
        // P3: read A(m2-3) buf0; stage B(t+2)->B0
        RDA2(2, A0OFF);
        if (!last) { STAGE1(pB0, kN2, B0OFF); STAGE1(pB1, kN2, B0OFF + 16384); }
        LGKM0();
        MFMAQ2(2, 2);
        // P4
        MFMAQ2(2, 0);
        if (last) { VMCNT(0); } else { VMCNT(4); }
        BARRIER();
        // P5: read A(m0-1)+B(n0-1) buf1; stage A(t+2)->A0
        RDA2(0, A1OFF); RDB2X(0, B1OFF);
        if (!last) STAGE1(pA, kN2, A0OFF);
        LGKM0();
        MFMAQ2(0, 0);
        // P6
        RDB2X(2, B1OFF);
        LGKM0();
        MFMAQ2(0, 2);
        BARRIER();
        // P7: read A(m2-3) buf1; stage B(t+3)->B1
        RDA2(2, A1OFF);
        if (!last) { STAGE1(pB0, kN3, B1OFF); STAGE1(pB1, kN3, B1OFF + 16384); }
        LGKM0();
        MFMAQ2(2, 2);
        // P8
        MFMAQ2(2, 0);
    }

    const int fr = lane & 15, fq = lane >> 4;
#pragma unroll
    for (int n = 0; n < 4; ++n) {
        const int c = col0 + wc * 64 + n * 16 + fr;
        const float bv = bias[c];
#pragma unroll
        for (int m = 0; m < 4; ++m) {
            const int rb = row0 + wr * 64 + m * 16 + fq * 4;
#pragma unroll
            for (int v = 0; v < 4; ++v)
                Cout[(size_t)(rb + v) * N + c] = acc[m][n][v] + bv;
        }
    }
#undef STAGE1
#undef RDA2
#undef RDB2X
#undef MFMAQ2
#undef A0OFF
#undef B0OFF
#undef A1OFF
#undef B1OFF
}

extern "C" void kernel_launch(void* const* d_in, const int* in_sizes, int n_in,
                              void* d_out, int out_size, void* d_ws, size_t ws_size,
                              hipStream_t stream) {
    const float* x  = (const float*)d_in[0];
    const float* rw = (const float*)d_in[1];
    const float* rb = (const float*)d_in[2];
    const float* w1 = (const float*)d_in[3];
    const float* b1 = (const float*)d_in[4];
    const float* w2 = (const float*)d_in[5];
    const float* b2 = (const float*)d_in[6];
    float* out = (float*)d_out;

    char* p = (char*)d_ws;
    auto take = [&](size_t bytes) { char* r = p; p += (bytes + 255) & ~(size_t)255; return r; };
    float* xsum          = (float*)take((size_t)B_ * D_ * sizeof(float));
    float* ew            = (float*)take(E_ * sizeof(float));
    float* mb1           = (float*)take(F_ * sizeof(float));
    float* mb2           = (float*)take(D_ * sizeof(float));
    unsigned short* xb   = (unsigned short*)take((size_t)B_ * S_ * D_ * 2);
    unsigned short* mw1b = (unsigned short*)take((size_t)F_ * D_ * 2);
    unsigned short* mw2b = (unsigned short*)take((size_t)D_ * F_ * 2);
    unsigned short* h    = (unsigned short*)take((size_t)B_ * S_ * F_ * 2);

    hipMemsetAsync(xsum, 0, (size_t)B_ * D_ * sizeof(float), stream);
    prep_x_kernel<<<dim3(128, B_), 256, 0, stream>>>(x, xb, xsum);
    router_kernel<<<1, 256, 0, stream>>>(xsum, rw, rb, ew);
    merge_all_kernel<<<4096, 256, 0, stream>>>(w1, w2, b1, b2, ew, mw1b, mw2b, mb1, mb2);
    // h = gelu(xb @ mw1b^T + mb1)   [M=8192, N=4096, K=1024]
    gemm256<<<dim3(F_ / 256, (B_ * S_) / 256), 512, 0, stream>>>(
        xb, mw1b, mb1, h, B_ * S_, F_, D_);
    // out = h @ mw2b^T + mb2        [M=8192, N=1024, K=4096]
    gemm128<<<dim3(D_ / 256, (B_ * S_) / 128), 512, 0, stream>>>(
        h, mw2b, mb2, out, B_ * S_, D_, F_);
}